// Round 1
// baseline (809.909 us; speedup 1.0000x reference)
//
#include <hip/hip_runtime.h>

// Problem constants (from reference setup_inputs)
#define BATCH 4
#define PTS   100000
#define CH    64
#define NPIX  (512 * 512)   // grid plane size; channel stride in floats

// One thread per point. Weights staged in LDS (Y_w transposed to [f][o] so the
// inner o-loop reads contiguous float4 at a wave-uniform address -> LDS
// broadcast, zero bank conflicts). 32 fp32 accumulators live in VGPRs; the
// 128-wide concat vector is never materialized.
__global__ __launch_bounds__(256) void unpillar_fused_kernel(
    const float* __restrict__ grid,  // (B, C, 512, 512)
    const float* __restrict__ pc,    // (B, P, C)
    const int*   __restrict__ idx,   // (B, P, C) -- broadcast along C
    const float* __restrict__ Yw,    // (32, 128) torch layout [out, in]
    const float* __restrict__ Yb,    // (32)
    const float* __restrict__ Zw,    // (3, 32)
    const float* __restrict__ Zb,    // (3)
    float* __restrict__ out)         // (B, P, 3)
{
    __shared__ float sYwT[128][32];  // [f][o] = Yw[o][f]
    __shared__ float sZw[3][32];
    __shared__ float sYb[32];
    __shared__ float sZb[3];

    const int t = threadIdx.x;

    // Cooperative weight staging (once per block; negligible traffic).
    for (int i = t; i < 128 * 32; i += 256) {
        int f = i >> 5;        // 0..127
        int o = i & 31;        // 0..31
        sYwT[f][o] = Yw[o * 128 + f];
    }
    for (int i = t; i < 96; i += 256) sZw[i / 32][i % 32] = Zw[i];
    if (t < 32) sYb[t] = Yb[t];
    if (t < 3)  sZb[t] = Zb[t];
    __syncthreads();

    const long long g = (long long)blockIdx.x * 256 + t;  // global point id
    if (g >= (long long)BATCH * PTS) return;
    const int b = (int)(g / PTS);
    const int p = (int)(g % PTS);

    // indices is (B, P, C) with the same value replicated across C: read ch 0.
    const int pillar = idx[((long long)b * PTS + p) * CH];

    const float* gb = grid + (size_t)b * CH * NPIX + pillar;  // + c*NPIX per ch
    const float* pb = pc + ((size_t)b * PTS + p) * CH;        // contiguous 64

    float acc[32];
#pragma unroll
    for (int o = 0; o < 32; ++o) acc[o] = sYb[o];

    // ---- first 64 features: gathered grid channels (weights Yw[:, 0..63])
    for (int c0 = 0; c0 < 64; c0 += 4) {
        // 4 independent scattered loads -> ILP for latency hiding
        float x0 = gb[(size_t)(c0 + 0) * NPIX];
        float x1 = gb[(size_t)(c0 + 1) * NPIX];
        float x2 = gb[(size_t)(c0 + 2) * NPIX];
        float x3 = gb[(size_t)(c0 + 3) * NPIX];
#pragma unroll
        for (int o4 = 0; o4 < 32; o4 += 4) {
            float4 w0 = *(const float4*)&sYwT[c0 + 0][o4];
            float4 w1 = *(const float4*)&sYwT[c0 + 1][o4];
            float4 w2 = *(const float4*)&sYwT[c0 + 2][o4];
            float4 w3 = *(const float4*)&sYwT[c0 + 3][o4];
            acc[o4 + 0] += x0 * w0.x + x1 * w1.x + x2 * w2.x + x3 * w3.x;
            acc[o4 + 1] += x0 * w0.y + x1 * w1.y + x2 * w2.y + x3 * w3.y;
            acc[o4 + 2] += x0 * w0.z + x1 * w1.z + x2 * w2.z + x3 * w3.z;
            acc[o4 + 3] += x0 * w0.w + x1 * w1.w + x2 * w2.w + x3 * w3.w;
        }
    }

    // ---- next 64 features: point cloud (weights Yw[:, 64..127]), float4 loads
    for (int c0 = 0; c0 < 64; c0 += 4) {
        float4 x = *(const float4*)&pb[c0];
        const int f = 64 + c0;
#pragma unroll
        for (int o4 = 0; o4 < 32; o4 += 4) {
            float4 w0 = *(const float4*)&sYwT[f + 0][o4];
            float4 w1 = *(const float4*)&sYwT[f + 1][o4];
            float4 w2 = *(const float4*)&sYwT[f + 2][o4];
            float4 w3 = *(const float4*)&sYwT[f + 3][o4];
            acc[o4 + 0] += x.x * w0.x + x.y * w1.x + x.z * w2.x + x.w * w3.x;
            acc[o4 + 1] += x.x * w0.y + x.y * w1.y + x.z * w2.y + x.w * w3.y;
            acc[o4 + 2] += x.x * w0.z + x.y * w1.z + x.z * w2.z + x.w * w3.z;
            acc[o4 + 3] += x.x * w0.w + x.y * w1.w + x.z * w2.w + x.w * w3.w;
        }
    }

    // ---- second layer: 32 -> 3
    float z0 = sZb[0], z1 = sZb[1], z2 = sZb[2];
#pragma unroll
    for (int o = 0; o < 32; ++o) {
        const float a = acc[o];
        z0 += a * sZw[0][o];
        z1 += a * sZw[1][o];
        z2 += a * sZw[2][o];
    }

    float* op = out + g * 3;
    op[0] = z0;
    op[1] = z1;
    op[2] = z2;
}

extern "C" void kernel_launch(void* const* d_in, const int* in_sizes, int n_in,
                              void* d_out, int out_size, void* d_ws, size_t ws_size,
                              hipStream_t stream) {
    const float* grid = (const float*)d_in[0];
    const float* pc   = (const float*)d_in[1];
    const int*   idx  = (const int*)d_in[2];
    const float* Yw   = (const float*)d_in[3];
    const float* Yb   = (const float*)d_in[4];
    const float* Zw   = (const float*)d_in[5];
    const float* Zb   = (const float*)d_in[6];
    float* out = (float*)d_out;

    const int total = BATCH * PTS;           // 400000
    const int blocks = (total + 255) / 256;  // 1563
    hipLaunchKernelGGL(unpillar_fused_kernel, dim3(blocks), dim3(256), 0, stream,
                       grid, pc, idx, Yw, Yb, Zw, Zb, out);
}

// Round 2
// 499.598 us; speedup vs baseline: 1.6211x; 1.6211x over previous
//
#include <hip/hip_runtime.h>

// Problem constants (from reference setup_inputs)
#define BATCH 4
#define PTS   100000
#define CH    64
#define NPIX  (512 * 512)   // 262144 pixels per plane

// The network is fully linear:
//   out[b,p,o] = sum_c Ag[o][c]*grid[b,c,pillar] + sum_c Ap[o][c]*pc[b,p,c] + bias2[o]
// where A = Zw @ Yw (3x128), Ag = A[:, :64], Ap = A[:, 64:], bias2 = Zw@Yb + Zb.
// The grid term depends only on the pillar -> precompute per-pixel G3 with a
// dense coalesced pass, turning the 1.65 GB scatter-gather into a 16 B gather
// from a 16.8 MB (mostly L3-resident) table.
//
// Workspace layout (d_ws):
//   [0)      float4 Ag4[64]   : Ag4[c] = {A[0][c],    A[1][c],    A[2][c],    0}
//   [1024)   float4 Ap4[64]   : Ap4[c] = {A[0][64+c], A[1][64+c], A[2][64+c], 0}
//   [2048)   float4 bias2     : {b0, b1, b2, 0}
//   [4096)   float4 G3[B*NPIX]: G3[b*NPIX+pix] = {g0, g1, g2, 0}   (16 MiB)

#define WS_AG    0
#define WS_AP    1024
#define WS_BIAS  2048
#define WS_G3    4096

// ---- K0: fold the two linear layers: A = Zw@Yw, bias2 = Zw@Yb + Zb ----
__global__ __launch_bounds__(128) void fold_weights_kernel(
    const float* __restrict__ Yw,   // (32,128)
    const float* __restrict__ Yb,   // (32)
    const float* __restrict__ Zw,   // (3,32)
    const float* __restrict__ Zb,   // (3)
    float* __restrict__ ws)
{
    const int f = threadIdx.x;  // 0..127
    float a0 = 0.f, a1 = 0.f, a2 = 0.f;
    for (int k = 0; k < 32; ++k) {
        const float y = Yw[k * 128 + f];   // coalesced
        a0 += Zw[0 * 32 + k] * y;
        a1 += Zw[1 * 32 + k] * y;
        a2 += Zw[2 * 32 + k] * y;
    }
    float4* dst = (f < 64) ? (float4*)((char*)ws + WS_AG) + f
                           : (float4*)((char*)ws + WS_AP) + (f - 64);
    *dst = make_float4(a0, a1, a2, 0.f);

    if (f == 0) {
        float b0 = Zb[0], b1 = Zb[1], b2 = Zb[2];
        for (int k = 0; k < 32; ++k) {
            const float y = Yb[k];
            b0 += Zw[0 * 32 + k] * y;
            b1 += Zw[1 * 32 + k] * y;
            b2 += Zw[2 * 32 + k] * y;
        }
        *(float4*)((char*)ws + WS_BIAS) = make_float4(b0, b1, b2, 0.f);
    }
}

// ---- K1: G3[b,pix,:] = Ag @ grid[b,:,pix]  (dense, coalesced) ----
// One thread per 4 pixels (float4 loads). grid read is streaming: for fixed c,
// consecutive threads read consecutive float4.
__global__ __launch_bounds__(256) void grid_reduce_kernel(
    const float* __restrict__ grid,  // (B, 64, NPIX)
    const float* __restrict__ ws_in,
    float* __restrict__ ws_out)
{
    __shared__ float4 sAg[64];
    if (threadIdx.x < 64)
        sAg[threadIdx.x] = ((const float4*)((const char*)ws_in + WS_AG))[threadIdx.x];
    __syncthreads();

    // blockIdx.x in [0, B*256): b = blockIdx.x >> 8
    const int b = blockIdx.x >> 8;
    const int grp = ((blockIdx.x & 255) << 8) | threadIdx.x;  // 0..65535: float4 group
    const size_t pix0 = (size_t)grp * 4;

    const float* gbase = grid + (size_t)b * CH * NPIX + pix0;

    float4 acc0 = make_float4(0.f, 0.f, 0.f, 0.f);  // output ch 0, 4 pixels
    float4 acc1 = acc0;                              // output ch 1
    float4 acc2 = acc0;                              // output ch 2
#pragma unroll 8
    for (int c = 0; c < 64; ++c) {
        const float4 g = *(const float4*)(gbase + (size_t)c * NPIX);
        const float4 a = sAg[c];
        acc0.x += g.x * a.x; acc0.y += g.y * a.x; acc0.z += g.z * a.x; acc0.w += g.w * a.x;
        acc1.x += g.x * a.y; acc1.y += g.y * a.y; acc1.z += g.z * a.y; acc1.w += g.w * a.y;
        acc2.x += g.x * a.z; acc2.y += g.y * a.z; acc2.z += g.z * a.z; acc2.w += g.w * a.z;
    }

    float4* out4 = (float4*)((char*)ws_out + WS_G3) + ((size_t)b * NPIX + pix0);
    out4[0] = make_float4(acc0.x, acc1.x, acc2.x, 0.f);
    out4[1] = make_float4(acc0.y, acc1.y, acc2.y, 0.f);
    out4[2] = make_float4(acc0.z, acc1.z, acc2.z, 0.f);
    out4[3] = make_float4(acc0.w, acc1.w, acc2.w, 0.f);
}

// ---- K2: per point: gather G3 (16 B) + pc dot + store ----
__global__ __launch_bounds__(256) void point_kernel(
    const float* __restrict__ pc,    // (B, P, 64)
    const int*   __restrict__ idx,   // (B, P, 64) broadcast along C
    const float* __restrict__ ws,
    float* __restrict__ out)         // (B, P, 3)
{
    __shared__ float4 sAp[64];
    __shared__ float4 sBias;
    if (threadIdx.x < 64)
        sAp[threadIdx.x] = ((const float4*)((const char*)ws + WS_AP))[threadIdx.x];
    if (threadIdx.x == 64)
        sBias = *(const float4*)((const char*)ws + WS_BIAS);
    __syncthreads();

    const long long g = (long long)blockIdx.x * 256 + threadIdx.x;
    if (g >= (long long)BATCH * PTS) return;
    const int b = (int)(g / PTS);
    const int p = (int)(g % PTS);

    const int pillar = idx[((long long)b * PTS + p) * CH];
    const float4 gcell = ((const float4*)((const char*)ws + WS_G3))[(size_t)b * NPIX + pillar];

    float z0 = gcell.x + sBias.x;
    float z1 = gcell.y + sBias.y;
    float z2 = gcell.z + sBias.z;

    const float4* pb = (const float4*)(pc + ((size_t)b * PTS + p) * CH);
#pragma unroll
    for (int c4 = 0; c4 < 16; ++c4) {
        const float4 x = pb[c4];
        const float4 a0 = sAp[c4 * 4 + 0];
        const float4 a1 = sAp[c4 * 4 + 1];
        const float4 a2 = sAp[c4 * 4 + 2];
        const float4 a3 = sAp[c4 * 4 + 3];
        z0 += x.x * a0.x + x.y * a1.x + x.z * a2.x + x.w * a3.x;
        z1 += x.x * a0.y + x.y * a1.y + x.z * a2.y + x.w * a3.y;
        z2 += x.x * a0.z + x.y * a1.z + x.z * a2.z + x.w * a3.z;
    }

    float* op = out + g * 3;
    op[0] = z0;
    op[1] = z1;
    op[2] = z2;
}

extern "C" void kernel_launch(void* const* d_in, const int* in_sizes, int n_in,
                              void* d_out, int out_size, void* d_ws, size_t ws_size,
                              hipStream_t stream) {
    const float* grid = (const float*)d_in[0];
    const float* pc   = (const float*)d_in[1];
    const int*   idx  = (const int*)d_in[2];
    const float* Yw   = (const float*)d_in[3];
    const float* Yb   = (const float*)d_in[4];
    const float* Zw   = (const float*)d_in[5];
    const float* Zb   = (const float*)d_in[6];
    float* out = (float*)d_out;
    float* ws  = (float*)d_ws;

    hipLaunchKernelGGL(fold_weights_kernel, dim3(1), dim3(128), 0, stream,
                       Yw, Yb, Zw, Zb, ws);

    // B * NPIX/4 threads = 262144 -> 1024 blocks of 256 (256 blocks per batch)
    hipLaunchKernelGGL(grid_reduce_kernel, dim3(BATCH * 256), dim3(256), 0, stream,
                       grid, ws, ws);

    const int total = BATCH * PTS;           // 400000
    const int blocks = (total + 255) / 256;  // 1563
    hipLaunchKernelGGL(point_kernel, dim3(blocks), dim3(256), 0, stream,
                       pc, idx, ws, out);
}